// Round 7
// baseline (1837.043 us; speedup 1.0000x reference)
//
#include <hip/hip_runtime.h>
#include <hip/hip_bf16.h>

#define KD 4096
#define ND 11008
#define MD 16384
#define KGD 32
#define NT (KD / 64)

typedef __hip_bfloat16 bf16;
typedef float f32x4 __attribute__((ext_vector_type(4)));
typedef float f32x16 __attribute__((ext_vector_type(16)));
typedef short bf16x8 __attribute__((ext_vector_type(8)));

#define WAITV(n) asm volatile("s_waitcnt vmcnt(" #n ")" ::: "memory")
#define BAR()    asm volatile("s_barrier" ::: "memory")

__device__ __forceinline__ void gload16(const bf16* g, bf16* l) {
    __builtin_amdgcn_global_load_lds((const __attribute__((address_space(1))) void*)g,
                                     (__attribute__((address_space(3))) void*)l, 16, 0, 0);
}

// ---------------------------------------------------------------------------
// x: fp32 -> bf16 (8 elems/thread)
// ---------------------------------------------------------------------------
__global__ void cvt_kernel(const float* __restrict__ x, bf16* __restrict__ y, int n8) {
    int i = blockIdx.x * blockDim.x + threadIdx.x;
    if (i >= n8) return;
    const f32x4* p = reinterpret_cast<const f32x4*>(x + (size_t)i * 8);
    f32x4 a = p[0], b = p[1];
    bf16 o[8];
#pragma unroll
    for (int e = 0; e < 4; ++e) {
        o[e]     = __float2bfloat16(a[e]);
        o[4 + e] = __float2bfloat16(b[e]);
    }
    *reinterpret_cast<bf16x8*>(y + (size_t)i * 8) = *reinterpret_cast<bf16x8*>(o);
}

// ---------------------------------------------------------------------------
// dequant packed int4 -> bf16 rows [n0 .. n0+rows) into wd (chunk-local)
// ---------------------------------------------------------------------------
__global__ void dequant_kernel(const int* __restrict__ wp, const float* __restrict__ sc,
                               bf16* __restrict__ wd, int n0, int rows) {
    const int per_row = KD / 8;
    int t = blockIdx.x * blockDim.x + threadIdx.x;
    if (t >= rows * per_row) return;
    int lr = t / per_row;
    int q  = t - lr * per_row;
    int n  = n0 + lr;
    int j  = q * 4;
    const int4 p = *reinterpret_cast<const int4*>(wp + (size_t)n * (KD / 2) + j);
    float s = sc[(size_t)n * KGD + (j >> 6)];
    int v[4] = {p.x, p.y, p.z, p.w};
    bf16 o[8];
#pragma unroll
    for (int i = 0; i < 4; ++i) {
        o[2 * i]     = __float2bfloat16((float)((v[i] & 0xF) - 8) * s);
        o[2 * i + 1] = __float2bfloat16((float)(((v[i] >> 4) & 0xF) - 8) * s);
    }
    *reinterpret_cast<bf16x8*>(wd + (size_t)lr * KD + j * 2) = *reinterpret_cast<bf16x8*>(o);
}

// ---------------------------------------------------------------------------
// GEMM: C[M,N] = A[M,K] * B[N,K]^T, bf16 in, fp32 out.
// 256x256 tile, 256 thr / 4 waves (2M x 2N), per-wave out 128x128 (4x4 frags
// of 32x32), mfma_f32_32x32x16_bf16, BK=64 (2 kh x 2 s K-steps).
// LDS [2buf][2kh][A/B][256x32] = 128 KiB, chunk swizzle c' = c ^ ((row>>1)&3)
// (uniform bank-group spread), staged via pre-swizzled global source.
// Per K-tile: BAR1 (all prior reads done) -> stage next tile (16 gload_lds)
// -> WAITV(16) counted (cur landed) -> BAR2 -> compute with ping-pong frag
// register sets (load batch g+1 issued before MFMA batch g -> LDS||MFMA).
// ---------------------------------------------------------------------------
__global__ __launch_bounds__(256, 1) void gemm256(const bf16* __restrict__ A,
                                                  const bf16* __restrict__ B,
                                                  float* __restrict__ C,
                                                  int mtiles, int ntiles, int n0base) {
    __shared__ bf16 lds[2][2][2][8192];  // [buf][kh][op][256 rows x 32 k, swizzled]
    const int tid  = threadIdx.x;
    const int lane = tid & 63;
    const int w    = tid >> 6;

    // bijective XCD-aware block swizzle
    int nwg = mtiles * ntiles;
    int orig = blockIdx.x;
    int q8 = nwg >> 3, r8 = nwg & 7;
    int xcd = orig & 7, off = orig >> 3;
    int wg = (xcd < r8 ? xcd * (q8 + 1) : r8 * (q8 + 1) + (xcd - r8) * q8) + off;
    const int mb = wg / ntiles, nb = wg - mb * ntiles;
    const int m0 = mb * 256, n0 = nb * 256;

    const int wm = w >> 1, wn = w & 1;
    const int r5 = lane & 31, kc = lane >> 5;   // frag row / k-chunk half
    const int q  = (r5 >> 1) & 3;
    const int co0 = ((kc) ^ q) * 8;             // swizzled chunk offset, s=0
    const int co1 = ((2 + kc) ^ q) * 8;         // s=1

    // staging source (pre-swizzled so linear gload_lds dest == swizzled layout)
    const int srow = w * 64 + (lane >> 2);
    const int scol = ((lane & 3) ^ ((lane >> 3) & 3)) * 8;
    const bf16* Ab = A + (size_t)(m0 + srow) * KD + scol;
    const bf16* Bb = B + (size_t)(n0 + srow) * KD + scol;

    f32x16 acc[4][4] = {};

    auto stage = [&](int b, int k0) {
#pragma unroll
        for (int kh = 0; kh < 2; ++kh) {
            const bf16* ga = Ab + k0 + kh * 32;
            const bf16* gb = Bb + k0 + kh * 32;
#pragma unroll
            for (int i = 0; i < 4; ++i) {
                gload16(ga + (size_t)(i * 16) * KD, &lds[b][kh][0][(w * 64 + i * 16) * 32]);
                gload16(gb + (size_t)(i * 16) * KD, &lds[b][kh][1][(w * 64 + i * 16) * 32]);
            }
        }
    };

    auto lA = [&](bf16x8* f, int b, int kh, int co) {
#pragma unroll
        for (int fm = 0; fm < 4; ++fm)
            f[fm] = *reinterpret_cast<const bf16x8*>(
                &lds[b][kh][0][(wm * 128 + fm * 32 + r5) * 32 + co]);
    };
    auto lB = [&](bf16x8* f, int b, int kh, int co) {
#pragma unroll
        for (int fn = 0; fn < 4; ++fn)
            f[fn] = *reinterpret_cast<const bf16x8*>(
                &lds[b][kh][1][(wn * 128 + fn * 32 + r5) * 32 + co]);
    };
    auto mm = [&](bf16x8* fa, bf16x8* fb) {
#pragma unroll
        for (int fm = 0; fm < 4; ++fm)
#pragma unroll
            for (int fn = 0; fn < 4; ++fn)
                acc[fm][fn] = __builtin_amdgcn_mfma_f32_32x32x16_bf16(
                    fa[fm], fb[fn], acc[fm][fn], 0, 0, 0);
    };

    auto compute = [&](int b) {
        bf16x8 fa0[4], fb0[4], fa1[4], fb1[4];
        lA(fa0, b, 0, co0); lB(fb0, b, 0, co0);   // batch g0
        lA(fa1, b, 0, co1); lB(fb1, b, 0, co1);   // batch g1 in flight
        mm(fa0, fb0);                              // MFMA g0
        lA(fa0, b, 1, co0); lB(fb0, b, 1, co0);   // batch g2 in flight
        mm(fa1, fb1);                              // MFMA g1
        lA(fa1, b, 1, co1); lB(fb1, b, 1, co1);   // batch g3 in flight
        mm(fa0, fb0);                              // MFMA g2
        mm(fa1, fb1);                              // MFMA g3
    };

    // prologue: tile 0 -> buf 0 (16 loads outstanding)
    stage(0, 0);

    for (int t = 0; t < NT - 1; ++t) {
        BAR();                          // all waves done reading buf[(t+1)&1] (iter t-1)
        stage((t + 1) & 1, (t + 1) * 64);   // WAR-safe; 32 outstanding
        WAITV(16);                      // own tile-t loads landed (16 newest = t+1)
        BAR();                          // => ALL waves' tile-t data landed
        compute(t & 1);
    }
    BAR();
    WAITV(0);
    BAR();
    compute((NT - 1) & 1);

    // epilogue: 32x32 C/D layout: col=lane&31, row=(reg&3)+8*(reg>>2)+4*(lane>>5)
    const int crow = m0 + wm * 128 + 4 * kc;
    const int ccol = n0base + n0 + wn * 128 + r5;
#pragma unroll
    for (int fm = 0; fm < 4; ++fm) {
#pragma unroll
        for (int fn = 0; fn < 4; ++fn) {
#pragma unroll
            for (int r = 0; r < 16; ++r) {
                int row = crow + fm * 32 + (r & 3) + 8 * (r >> 2);
                C[(size_t)row * ND + ccol + fn * 32] = acc[fm][fn][r];
            }
        }
    }
}

extern "C" void kernel_launch(void* const* d_in, const int* in_sizes, int n_in,
                              void* d_out, int out_size, void* d_ws, size_t ws_size,
                              hipStream_t stream) {
    const float* x  = (const float*)d_in[0];
    const int*   wp = (const int*)d_in[1];
    const float* sc = (const float*)d_in[2];
    float* out = (float*)d_out;

    // partition ws into x-bf16 chunk (mc rows) + W-bf16 chunk (nc rows), both x256
    long long rows_cap = (long long)(ws_size / ((size_t)KD * 2));
    int mc, nc;
    if (rows_cap >= MD + 256) {
        mc = MD;
        long long r = rows_cap - MD;
        nc = (int)((r / 256) * 256);
        if (nc > ND) nc = ND;
    } else if (rows_cap >= ND + 256) {
        nc = ND;
        long long r = rows_cap - ND;
        mc = (int)((r / 256) * 256);
        if (mc > MD) mc = MD;
    } else {
        nc = (int)(((rows_cap / 2) / 256) * 256);
        if (nc > ND) nc = ND;
        long long r = rows_cap - nc;
        mc = (int)((r / 256) * 256);
        if (mc > MD) mc = MD;
        if (mc <= 0 || nc <= 0) return;
    }

    bf16* xbuf = (bf16*)d_ws;
    bf16* wbuf = xbuf + (size_t)mc * KD;

    for (int m0 = 0; m0 < MD; m0 += mc) {
        int mrows = (MD - m0 < mc) ? (MD - m0) : mc;   // multiple of 256
        int n8 = mrows * (KD / 8);
        cvt_kernel<<<(n8 + 255) / 256, 256, 0, stream>>>(x + (size_t)m0 * KD, xbuf, n8);
        for (int n0 = 0; n0 < ND; n0 += nc) {
            int nrows = (ND - n0 < nc) ? (ND - n0) : nc;  // multiple of 256
            int tt = nrows * (KD / 8);
            dequant_kernel<<<(tt + 255) / 256, 256, 0, stream>>>(wp, sc, wbuf, n0, nrows);
            int mt = mrows / 256, nt2 = nrows / 256;
            gemm256<<<mt * nt2, 256, 0, stream>>>(xbuf, wbuf, out + (size_t)m0 * ND, mt, nt2, n0);
        }
    }
}